// Round 1
// baseline (436.708 us; speedup 1.0000x reference)
//
#include <hip/hip_runtime.h>
#include <hip/hip_bf16.h>
#include <cstdint>
#include <cstddef>

#define B_     2
#define E_     196608
#define XD_    128
#define NREC_  12288
#define EOUT_  128
#define LIN_   256
#define LOUT_  256
#define M_     (B_ * NREC_)   // 24576 FFN rows

typedef __attribute__((ext_vector_type(8))) short short8;
typedef __attribute__((ext_vector_type(4))) float f32x4;

__device__ __forceinline__ unsigned short f2bf(float f) {
    union { float f; unsigned u; } v; v.f = f;
    unsigned r = v.u + 0x7FFFu + ((v.u >> 16) & 1u);
    return (unsigned short)(r >> 16);
}

// ---- transpose + bf16-convert FFN weights: L1T[n][k] = bf16(L1[k][n]) ----
__global__ __launch_bounds__(256) void convert_w(const float* __restrict__ L1,
                                                 const float* __restrict__ L2,
                                                 unsigned short* __restrict__ L1T,
                                                 unsigned short* __restrict__ L2T) {
    int idx = blockIdx.x * 256 + threadIdx.x;   // 0..65535
    int k = idx >> 8, n = idx & 255;
    L1T[n * 256 + k] = f2bf(L1[idx]);
    L2T[n * 256 + k] = f2bf(L2[idx]);
}

// ---- histogram of receivers ----
__global__ __launch_bounds__(256) void count_kernel(const int* __restrict__ recv,
                                                    int* __restrict__ cnt) {
    int e = blockIdx.x * 256 + threadIdx.x;
    if (e < E_) atomicAdd(&cnt[recv[e]], 1);
}

// ---- exclusive scan over 12288 counts (single block, 1024 thr x 12 items) ----
__global__ __launch_bounds__(1024) void scan_kernel(const int* __restrict__ cnt,
                                                    int* __restrict__ rowStart,
                                                    int* __restrict__ cursor) {
    __shared__ int sums[1024];
    int tid = threadIdx.x;
    int base = tid * 12;
    int local[12];
    int s = 0;
    #pragma unroll
    for (int j = 0; j < 12; ++j) { local[j] = s; s += cnt[base + j]; }
    sums[tid] = s;
    __syncthreads();
    for (int off = 1; off < 1024; off <<= 1) {
        int v = sums[tid];
        int add = (tid >= off) ? sums[tid - off] : 0;
        __syncthreads();
        sums[tid] = v + add;
        __syncthreads();
    }
    int excl = (tid == 0) ? 0 : sums[tid - 1];
    #pragma unroll
    for (int j = 0; j < 12; ++j) {
        int v = excl + local[j];
        rowStart[base + j] = v;
        cursor[base + j] = v;
    }
    if (tid == 1023) rowStart[NREC_] = excl + s;   // == E_
}

// ---- fill CSR edge id lists ----
__global__ __launch_bounds__(256) void fill_kernel(const int* __restrict__ recv,
                                                   int* __restrict__ cursor,
                                                   int* __restrict__ edge_ids) {
    int e = blockIdx.x * 256 + threadIdx.x;
    if (e < E_) {
        int p = atomicAdd(&cursor[recv[e]], 1);
        edge_ids[p] = e;
    }
}

// ---- fused: edge-MLP layer1 + segment-sum + @W2 + n*b2, pack agg as bf16 ----
// agg_bf layout: [B][NREC][256]; cols 0..127 = h part (batch-independent),
// cols 128..255 = x part.
__global__ __launch_bounds__(128) void gather_kernel(
        const float* __restrict__ x, const float* __restrict__ ea,
        const float* __restrict__ W1, const float* __restrict__ b1,
        const float* __restrict__ W2, const float* __restrict__ b2,
        const int* __restrict__ rowStart, const int* __restrict__ edge_ids,
        unsigned short* __restrict__ agg_bf) {
    __shared__ float s1row[128];
    int r = blockIdx.x;
    int c = threadIdx.x;           // 0..127
    int k0 = rowStart[r], k1 = rowStart[r + 1];
    float w10 = W1[c], w11 = W1[128 + c], w12 = W1[256 + c], w13 = W1[384 + c];
    float bb1 = b1[c];
    float accS1 = 0.f, accX0 = 0.f, accX1 = 0.f;
    for (int k = k0; k < k1; ++k) {
        int e = edge_ids[k];
        float e0 = ea[e * 4 + 0], e1 = ea[e * 4 + 1];
        float e2 = ea[e * 4 + 2], e3 = ea[e * 4 + 3];
        float p = fmaf(e0, w10, fmaf(e1, w11, fmaf(e2, w12, fmaf(e3, w13, bb1))));
        float sv = p / (1.f + __expf(-p));      // silu
        accS1 += sv;
        accX0 += x[(size_t)e * 128 + c];
        accX1 += x[(size_t)E_ * 128 + (size_t)e * 128 + c];
    }
    s1row[c] = accS1;
    __syncthreads();
    // aggH = (sum silu1) @ W2 + n_r * b2   (linearity of segment_sum)
    float accH = (float)(k1 - k0) * b2[c];
    for (int j = 0; j < 128; ++j)
        accH = fmaf(s1row[j], W2[j * 128 + c], accH);
    unsigned short hb = f2bf(accH);
    agg_bf[(size_t)r * 256 + c] = hb;
    agg_bf[(size_t)(NREC_ + r) * 256 + c] = hb;
    agg_bf[(size_t)r * 256 + 128 + c] = f2bf(accX0);
    agg_bf[(size_t)(NREC_ + r) * 256 + 128 + c] = f2bf(accX1);
}

// ---- output FFN: out = silu(agg @ L1 + c1) @ L2 + c2, bf16 MFMA 16x16x32 ----
// Each block: 64 rows (4 waves x 16 rows). Weights pre-transposed [n][k] bf16.
__global__ __launch_bounds__(256) void ffn_kernel(
        const unsigned short* __restrict__ agg,
        const unsigned short* __restrict__ L1T, const float* __restrict__ c1,
        const unsigned short* __restrict__ L2T, const float* __restrict__ c2,
        float* __restrict__ out) {
    __shared__ unsigned short T[64][264];   // padded: 264*2=528B row, +4 dword skew
    int tid  = threadIdx.x;
    int wave = tid >> 6;
    int lane = tid & 63;
    int quad = lane >> 4;      // 0..3
    int l16  = lane & 15;      // 0..15
    int m0 = blockIdx.x * 64 + wave * 16;   // this wave's global row base

    // A fragments for layer 1: A[m=l16][k = ks*32 + quad*8 + j]
    short8 afrag[8];
    const unsigned short* aptr = agg + (size_t)(m0 + l16) * 256 + quad * 8;
    #pragma unroll
    for (int ks = 0; ks < 8; ++ks)
        afrag[ks] = *(const short8*)(aptr + ks * 32);

    // layer 1: 16 n-tiles of 16 cols, K=256 in 8 steps of 32
    #pragma unroll 2
    for (int nt = 0; nt < 16; ++nt) {
        f32x4 acc = {0.f, 0.f, 0.f, 0.f};
        const unsigned short* bptr = L1T + (size_t)(nt * 16 + l16) * 256 + quad * 8;
        #pragma unroll
        for (int ks = 0; ks < 8; ++ks) {
            short8 bfrag = *(const short8*)(bptr + ks * 32);
            acc = __builtin_amdgcn_mfma_f32_16x16x32_bf16(afrag[ks], bfrag, acc, 0, 0, 0);
        }
        #pragma unroll
        for (int rr = 0; rr < 4; ++rr) {
            int row = quad * 4 + rr;          // D: row = quad*4+reg, col = l16
            int col = nt * 16 + l16;
            float v = acc[rr] + c1[col];
            v = v / (1.f + __expf(-v));       // silu
            T[wave * 16 + row][col] = f2bf(v);
        }
    }
    __syncthreads();

    // layer 2: A from LDS (each wave reads only its own 16 rows)
    short8 afrag2[8];
    #pragma unroll
    for (int ks = 0; ks < 8; ++ks)
        afrag2[ks] = *(const short8*)&T[wave * 16 + l16][ks * 32 + quad * 8];

    #pragma unroll 2
    for (int nt = 0; nt < 16; ++nt) {
        f32x4 acc = {0.f, 0.f, 0.f, 0.f};
        const unsigned short* bptr = L2T + (size_t)(nt * 16 + l16) * 256 + quad * 8;
        #pragma unroll
        for (int ks = 0; ks < 8; ++ks) {
            short8 bfrag = *(const short8*)(bptr + ks * 32);
            acc = __builtin_amdgcn_mfma_f32_16x16x32_bf16(afrag2[ks], bfrag, acc, 0, 0, 0);
        }
        #pragma unroll
        for (int rr = 0; rr < 4; ++rr) {
            int row = m0 + quad * 4 + rr;
            int col = nt * 16 + l16;
            out[(size_t)row * 256 + col] = acc[rr] + c2[col];
        }
    }
}

extern "C" void kernel_launch(void* const* d_in, const int* in_sizes, int n_in,
                              void* d_out, int out_size, void* d_ws, size_t ws_size,
                              hipStream_t stream) {
    const float* x          = (const float*)d_in[0];
    const float* edge_attr  = (const float*)d_in[1];
    const int*   edge_index = (const int*)d_in[2];
    const float* W1 = (const float*)d_in[3];
    const float* b1 = (const float*)d_in[4];
    const float* W2 = (const float*)d_in[5];
    const float* b2 = (const float*)d_in[6];
    const float* L1 = (const float*)d_in[7];
    const float* c1 = (const float*)d_in[8];
    const float* L2 = (const float*)d_in[9];
    const float* c2 = (const float*)d_in[10];
    float* out = (float*)d_out;

    // workspace layout (all 16B aligned)
    int* cnt      = (int*)d_ws;                 // 12288
    int* rowStart = cnt + NREC_;                // 12289 (padded to 12292)
    int* cursor   = rowStart + NREC_ + 4;       // 12288
    int* edge_ids = cursor + NREC_;             // 196608
    unsigned short* agg_bf = (unsigned short*)(edge_ids + E_);   // 2*12288*256
    unsigned short* L1T = agg_bf + (size_t)M_ * 256;             // 65536
    unsigned short* L2T = L1T + 256 * 256;                       // 65536

    const int* recv = edge_index + E_;   // edge_index[1]

    hipMemsetAsync(cnt, 0, NREC_ * sizeof(int), stream);
    convert_w<<<256, 256, 0, stream>>>(L1, L2, L1T, L2T);
    count_kernel<<<(E_ + 255) / 256, 256, 0, stream>>>(recv, cnt);
    scan_kernel<<<1, 1024, 0, stream>>>(cnt, rowStart, cursor);
    fill_kernel<<<(E_ + 255) / 256, 256, 0, stream>>>(recv, cursor, edge_ids);
    gather_kernel<<<NREC_, 128, 0, stream>>>(x, edge_attr, W1, b1, W2, b2,
                                             rowStart, edge_ids, agg_bf);
    ffn_kernel<<<M_ / 64, 256, 0, stream>>>(agg_bf, L1T, c1, L2T, c2, out);
}

// Round 2
// 411.998 us; speedup vs baseline: 1.0600x; 1.0600x over previous
//
#include <hip/hip_runtime.h>
#include <hip/hip_bf16.h>
#include <cstdint>
#include <cstddef>

#define B_     2
#define E_     196608
#define XD_    128
#define NREC_  12288
#define EOUT_  128
#define LIN_   256
#define LOUT_  256
#define M_     (B_ * NREC_)   // 24576 FFN rows

typedef __attribute__((ext_vector_type(8))) short short8;
typedef __attribute__((ext_vector_type(4))) float f32x4;

__device__ __forceinline__ unsigned short f2bf(float f) {
    union { float f; unsigned u; } v; v.f = f;
    unsigned r = v.u + 0x7FFFu + ((v.u >> 16) & 1u);
    return (unsigned short)(r >> 16);
}

// ---- precompute combined FFN weights ----
// L1T[n][k] (bf16, k-major rows for MFMA B-frags):
//   k <  128 : M1[k][n] = sum_c W2[k][c] * L1[c][n]   (W2 folded into L1 top)
//   k >= 128 : L1[k][n]                                (x part unchanged)
// L2T[n][k] = L2[k][n]
// v[n] = sum_c b2[c] * L1[c][n]   (scaled by per-row edge count in ffn)
__global__ __launch_bounds__(256) void precompute(
        const float* __restrict__ W2, const float* __restrict__ b2,
        const float* __restrict__ L1, const float* __restrict__ L2,
        unsigned short* __restrict__ L1T, unsigned short* __restrict__ L2T,
        float* __restrict__ v) {
    int bid = blockIdx.x;
    int n = threadIdx.x;    // 0..255
    if (bid < 128) {
        int j = bid;
        float a0 = 0.f, a1 = 0.f, a2 = 0.f, a3 = 0.f;
        for (int c = 0; c < 128; c += 4) {
            a0 = fmaf(W2[j * 128 + c + 0], L1[(c + 0) * 256 + n], a0);
            a1 = fmaf(W2[j * 128 + c + 1], L1[(c + 1) * 256 + n], a1);
            a2 = fmaf(W2[j * 128 + c + 2], L1[(c + 2) * 256 + n], a2);
            a3 = fmaf(W2[j * 128 + c + 3], L1[(c + 3) * 256 + n], a3);
        }
        L1T[n * 256 + j] = f2bf((a0 + a1) + (a2 + a3));
        if (j == 0) {
            float s0 = 0.f, s1 = 0.f;
            for (int c = 0; c < 128; c += 2) {
                s0 = fmaf(b2[c + 0], L1[(c + 0) * 256 + n], s0);
                s1 = fmaf(b2[c + 1], L1[(c + 1) * 256 + n], s1);
            }
            v[n] = s0 + s1;
        }
    } else if (bid < 256) {
        int k = bid;                          // 128..255
        L1T[n * 256 + k] = f2bf(L1[k * 256 + n]);
    } else {
        int k = bid - 256;                    // 0..255
        L2T[n * 256 + k] = f2bf(L2[k * 256 + n]);
    }
}

// ---- histogram of receivers ----
__global__ __launch_bounds__(256) void count_kernel(const int* __restrict__ recv,
                                                    int* __restrict__ cnt) {
    int e = blockIdx.x * 256 + threadIdx.x;
    if (e < E_) atomicAdd(&cnt[recv[e]], 1);
}

// ---- exclusive scan over 12288 counts (single block, 1024 thr x 12 items) ----
__global__ __launch_bounds__(1024) void scan_kernel(const int* __restrict__ cnt,
                                                    int* __restrict__ rowStart,
                                                    int* __restrict__ cursor) {
    __shared__ int sums[1024];
    int tid = threadIdx.x;
    int base = tid * 12;
    int local[12];
    int s = 0;
    #pragma unroll
    for (int j = 0; j < 12; ++j) { local[j] = s; s += cnt[base + j]; }
    sums[tid] = s;
    __syncthreads();
    for (int off = 1; off < 1024; off <<= 1) {
        int vv = sums[tid];
        int add = (tid >= off) ? sums[tid - off] : 0;
        __syncthreads();
        sums[tid] = vv + add;
        __syncthreads();
    }
    int excl = (tid == 0) ? 0 : sums[tid - 1];
    #pragma unroll
    for (int j = 0; j < 12; ++j) {
        int vv = excl + local[j];
        rowStart[base + j] = vv;
        cursor[base + j] = vv;
    }
    if (tid == 1023) rowStart[NREC_] = excl + s;   // == E_
}

// ---- fill CSR edge id lists ----
__global__ __launch_bounds__(256) void fill_kernel(const int* __restrict__ recv,
                                                   int* __restrict__ cursor,
                                                   int* __restrict__ edge_ids) {
    int e = blockIdx.x * 256 + threadIdx.x;
    if (e < E_) {
        int p = atomicAdd(&cursor[recv[e]], 1);
        edge_ids[p] = e;
    }
}

// ---- fused gather: per receiver, sum silu(ea@W1+b1) and x rows; bf16 pack ----
// agg layout: [B][NREC][256]; cols 0..127 = S (batch-independent, duplicated),
// cols 128..255 = x sum per batch. 8-wide edge unroll for MLP.
__global__ __launch_bounds__(128) void gather_kernel(
        const float* __restrict__ x, const float* __restrict__ ea,
        const float* __restrict__ W1, const float* __restrict__ b1,
        const int* __restrict__ rowStart, const int* __restrict__ edge_ids,
        unsigned short* __restrict__ agg_bf) {
    int r = blockIdx.x;
    int c = threadIdx.x;           // 0..127
    int k0 = __builtin_amdgcn_readfirstlane(rowStart[r]);
    int k1 = __builtin_amdgcn_readfirstlane(rowStart[r + 1]);
    float w10 = W1[c], w11 = W1[128 + c], w12 = W1[256 + c], w13 = W1[384 + c];
    float bb1 = b1[c];
    const float* xb = x + (size_t)E_ * 128;
    float accS = 0.f, aX0 = 0.f, aX1 = 0.f;
    int k = k0;
    for (; k + 8 <= k1; k += 8) {
        int e[8];
        #pragma unroll
        for (int u = 0; u < 8; ++u)
            e[u] = __builtin_amdgcn_readfirstlane(edge_ids[k + u]);
        float xa[8], xc[8];
        float4 q[8];
        #pragma unroll
        for (int u = 0; u < 8; ++u) {
            xa[u] = x[(size_t)e[u] * 128 + c];
            xc[u] = xb[(size_t)e[u] * 128 + c];
            q[u] = *(const float4*)(ea + (size_t)e[u] * 4);
        }
        #pragma unroll
        for (int u = 0; u < 8; ++u) {
            float p = fmaf(q[u].x, w10, fmaf(q[u].y, w11,
                      fmaf(q[u].z, w12, fmaf(q[u].w, w13, bb1))));
            accS += p / (1.f + __expf(-p));
            aX0 += xa[u];
            aX1 += xc[u];
        }
    }
    for (; k < k1; ++k) {
        int e0 = __builtin_amdgcn_readfirstlane(edge_ids[k]);
        float4 q = *(const float4*)(ea + (size_t)e0 * 4);
        float p = fmaf(q.x, w10, fmaf(q.y, w11, fmaf(q.z, w12, fmaf(q.w, w13, bb1))));
        accS += p / (1.f + __expf(-p));
        aX0 += x[(size_t)e0 * 128 + c];
        aX1 += xb[(size_t)e0 * 128 + c];
    }
    unsigned short sb = f2bf(accS);
    agg_bf[(size_t)r * 256 + c] = sb;
    agg_bf[(size_t)(NREC_ + r) * 256 + c] = sb;
    agg_bf[(size_t)r * 256 + 128 + c] = f2bf(aX0);
    agg_bf[(size_t)(NREC_ + r) * 256 + 128 + c] = f2bf(aX1);
}

// ---- output FFN: out = silu(agg @ L1comb + c1 + cnt*v) @ L2 + c2 ----
// bf16 MFMA 16x16x32. Each block: 64 rows (4 waves x 16 rows).
__global__ __launch_bounds__(256) void ffn_kernel(
        const unsigned short* __restrict__ agg,
        const unsigned short* __restrict__ L1T, const float* __restrict__ c1,
        const unsigned short* __restrict__ L2T, const float* __restrict__ c2,
        const float* __restrict__ v, const int* __restrict__ cnt,
        float* __restrict__ out) {
    __shared__ unsigned short T[64][264];
    int tid  = threadIdx.x;
    int wave = tid >> 6;
    int lane = tid & 63;
    int quad = lane >> 4;
    int l16  = lane & 15;
    int m0 = blockIdx.x * 64 + wave * 16;

    float cntv[4];
    #pragma unroll
    for (int rr = 0; rr < 4; ++rr) {
        int m = m0 + quad * 4 + rr;
        int r = (m >= NREC_) ? m - NREC_ : m;
        cntv[rr] = (float)cnt[r];
    }

    // A fragments for layer 1: A[m=l16][k = ks*32 + quad*8 + j]
    short8 afrag[8];
    const unsigned short* aptr = agg + (size_t)(m0 + l16) * 256 + quad * 8;
    #pragma unroll
    for (int ks = 0; ks < 8; ++ks)
        afrag[ks] = *(const short8*)(aptr + ks * 32);

    #pragma unroll 2
    for (int nt = 0; nt < 16; ++nt) {
        f32x4 acc = {0.f, 0.f, 0.f, 0.f};
        const unsigned short* bptr = L1T + (size_t)(nt * 16 + l16) * 256 + quad * 8;
        #pragma unroll
        for (int ks = 0; ks < 8; ++ks) {
            short8 bfrag = *(const short8*)(bptr + ks * 32);
            acc = __builtin_amdgcn_mfma_f32_16x16x32_bf16(afrag[ks], bfrag, acc, 0, 0, 0);
        }
        #pragma unroll
        for (int rr = 0; rr < 4; ++rr) {
            int row = quad * 4 + rr;
            int col = nt * 16 + l16;
            float pv = acc[rr] + c1[col] + cntv[rr] * v[col];
            pv = pv / (1.f + __expf(-pv));
            T[wave * 16 + row][col] = f2bf(pv);
        }
    }
    __syncthreads();

    short8 afrag2[8];
    #pragma unroll
    for (int ks = 0; ks < 8; ++ks)
        afrag2[ks] = *(const short8*)&T[wave * 16 + l16][ks * 32 + quad * 8];

    #pragma unroll 2
    for (int nt = 0; nt < 16; ++nt) {
        f32x4 acc = {0.f, 0.f, 0.f, 0.f};
        const unsigned short* bptr = L2T + (size_t)(nt * 16 + l16) * 256 + quad * 8;
        #pragma unroll
        for (int ks = 0; ks < 8; ++ks) {
            short8 bfrag = *(const short8*)(bptr + ks * 32);
            acc = __builtin_amdgcn_mfma_f32_16x16x32_bf16(afrag2[ks], bfrag, acc, 0, 0, 0);
        }
        #pragma unroll
        for (int rr = 0; rr < 4; ++rr) {
            int row = m0 + quad * 4 + rr;
            int col = nt * 16 + l16;
            out[(size_t)row * 256 + col] = acc[rr] + c2[col];
        }
    }
}

extern "C" void kernel_launch(void* const* d_in, const int* in_sizes, int n_in,
                              void* d_out, int out_size, void* d_ws, size_t ws_size,
                              hipStream_t stream) {
    const float* x          = (const float*)d_in[0];
    const float* edge_attr  = (const float*)d_in[1];
    const int*   edge_index = (const int*)d_in[2];
    const float* W1 = (const float*)d_in[3];
    const float* b1 = (const float*)d_in[4];
    const float* W2 = (const float*)d_in[5];
    const float* b2 = (const float*)d_in[6];
    const float* L1 = (const float*)d_in[7];
    const float* c1 = (const float*)d_in[8];
    const float* L2 = (const float*)d_in[9];
    const float* c2 = (const float*)d_in[10];
    float* out = (float*)d_out;

    // workspace layout (16B aligned)
    int* cnt      = (int*)d_ws;                 // 12288
    int* rowStart = cnt + NREC_;                // 12289 (pad to 12292)
    int* cursor   = rowStart + NREC_ + 4;       // 12288
    int* edge_ids = cursor + NREC_;             // 196608
    unsigned short* agg_bf = (unsigned short*)(edge_ids + E_);   // M_*256
    unsigned short* L1T = agg_bf + (size_t)M_ * 256;             // 65536
    unsigned short* L2T = L1T + 256 * 256;                       // 65536
    float* v = (float*)(L2T + 256 * 256);                        // 256

    const int* recv = edge_index + E_;   // edge_index[1]

    hipMemsetAsync(cnt, 0, NREC_ * sizeof(int), stream);
    precompute<<<512, 256, 0, stream>>>(W2, b2, L1, L2, L1T, L2T, v);
    count_kernel<<<(E_ + 255) / 256, 256, 0, stream>>>(recv, cnt);
    scan_kernel<<<1, 1024, 0, stream>>>(cnt, rowStart, cursor);
    fill_kernel<<<(E_ + 255) / 256, 256, 0, stream>>>(recv, cursor, edge_ids);
    gather_kernel<<<NREC_, 128, 0, stream>>>(x, edge_attr, W1, b1,
                                             rowStart, edge_ids, agg_bf);
    ffn_kernel<<<M_ / 64, 256, 0, stream>>>(agg_bf, L1T, c1, L2T, c2, v, cnt, out);
}